// Round 1
// baseline (566.774 us; speedup 1.0000x reference)
//
#include <hip/hip_runtime.h>

#define S_LEN  4096
#define DMODEL 1024
#define NHEAD  16
#define HDIM   64

typedef float    f32x4  __attribute__((ext_vector_type(4)));
typedef _Float16 f16x8  __attribute__((ext_vector_type(8)));
typedef _Float16 f16x4v __attribute__((ext_vector_type(4)));

// ---------------------------------------------------------------- helpers
__device__ __forceinline__ void gl2lds16(const _Float16* g, _Float16* l) {
  // async global->LDS, 16B per lane, LDS dest = uniform base + lane*16
  __builtin_amdgcn_global_load_lds(
      (const __attribute__((address_space(1))) unsigned int*)g,
      (__attribute__((address_space(3))) unsigned int*)l, 16, 0, 0);
}

// ---------------------------------------------------------------- cast f32 -> f16
__global__ void cast_f32_f16_k(const float* __restrict__ in,
                               _Float16* __restrict__ out, int n) {
  int i = (blockIdx.x * blockDim.x + threadIdx.x) * 4;
  if (i + 3 < n) {
    const float4 v = *(const float4*)(in + i);
    f16x4v o = { (_Float16)v.x, (_Float16)v.y, (_Float16)v.z, (_Float16)v.w };
    *(f16x4v*)(out + i) = o;
  }
}

// ---------------------------------------------------------------- GEMM  y = A @ W^T (+bias) (+RoPE)
// A  : [M][K] f16 row-major
// Bw : [N][K] f16 row-major (nn.Linear weight)
// MODE 0: bf/f16 out [M][N], +bias, +CT-RoPE (Q,K)
// MODE 1: f16 out transposed [N][M], +bias (V -> Vt)
// MODE 2: f32 out [M][N], no bias (final O-proj -> d_out)
template<int MODE>
__global__ __launch_bounds__(256)
void gemm128(const _Float16* __restrict__ A,
             const _Float16* __restrict__ Bw,
             const float* __restrict__ bias,
             const float* __restrict__ ts,
             void* __restrict__ outp,
             int M, int N, int K)
{
  __shared__ _Float16 lA[128 * 64];
  __shared__ _Float16 lB[128 * 64];

  const int tid  = threadIdx.x;
  const int wid  = tid >> 6;
  const int lane = tid & 63;
  const int l16  = lane & 15;
  const int lg   = lane >> 4;
  const int wr = wid >> 1, wc = wid & 1;
  const int m0 = blockIdx.y * 128, n0 = blockIdx.x * 128;

  const int lrow   = lane >> 3;           // 0..7 rows per 1KB wave chunk
  const int gchunk = (lane & 7) ^ lrow;   // pre-swizzled global chunk (T2, rule 21)

  f32x4 acc[4][4] = {};

  for (int k0 = 0; k0 < K; k0 += 64) {
#pragma unroll
    for (int it = 0; it < 4; ++it) {
      const int rbase = (it * 4 + wid) * 8;
      gl2lds16(A  + (size_t)(m0 + rbase + lrow) * K + k0 + gchunk * 8, &lA[rbase * 64]);
      gl2lds16(Bw + (size_t)(n0 + rbase + lrow) * K + k0 + gchunk * 8, &lB[rbase * 64]);
    }
    __syncthreads();
#pragma unroll
    for (int kk = 0; kk < 2; ++kk) {
      f16x8 af[4], bfr[4];
#pragma unroll
      for (int mr = 0; mr < 4; ++mr) {
        const int row = wr * 64 + mr * 16 + l16;
        const int ch  = (kk * 4 + lg) ^ (l16 & 7);
        af[mr] = *(const f16x8*)&lA[row * 64 + ch * 8];
      }
#pragma unroll
      for (int nr = 0; nr < 4; ++nr) {
        const int row = wc * 64 + nr * 16 + l16;
        const int ch  = (kk * 4 + lg) ^ (l16 & 7);
        bfr[nr] = *(const f16x8*)&lB[row * 64 + ch * 8];
      }
#pragma unroll
      for (int mr = 0; mr < 4; ++mr)
#pragma unroll
        for (int nr = 0; nr < 4; ++nr)
          acc[mr][nr] = __builtin_amdgcn_mfma_f32_16x16x32_f16(af[mr], bfr[nr], acc[mr][nr], 0, 0, 0);
    }
    __syncthreads();
  }

  // ---------------- epilogue ----------------
  if (MODE == 2) {
    float* O = (float*)outp;
#pragma unroll
    for (int mr = 0; mr < 4; ++mr)
#pragma unroll
      for (int r = 0; r < 4; ++r) {
        const int m = m0 + wr * 64 + mr * 16 + lg * 4 + r;
#pragma unroll
        for (int nr = 0; nr < 4; ++nr) {
          const int n = n0 + wc * 64 + nr * 16 + l16;
          O[(size_t)m * N + n] = acc[mr][nr][r];
        }
      }
  } else if (MODE == 1) {
    _Float16* O = (_Float16*)outp;   // [N][M] transposed V
    float bv[4];
#pragma unroll
    for (int nr = 0; nr < 4; ++nr) bv[nr] = bias[n0 + wc * 64 + nr * 16 + l16];
#pragma unroll
    for (int mr = 0; mr < 4; ++mr) {
      const int mbase = m0 + wr * 64 + mr * 16 + lg * 4;
#pragma unroll
      for (int nr = 0; nr < 4; ++nr) {
        const int n = n0 + wc * 64 + nr * 16 + l16;
        f16x4v o = { (_Float16)(acc[mr][nr][0] + bv[nr]),
                     (_Float16)(acc[mr][nr][1] + bv[nr]),
                     (_Float16)(acc[mr][nr][2] + bv[nr]),
                     (_Float16)(acc[mr][nr][3] + bv[nr]) };
        *(f16x4v*)&O[(size_t)n * M + mbase] = o;
      }
    }
  } else { // MODE 0: bias + CT-RoPE, f16 out [M][N]
    _Float16* O = (_Float16*)outp;
    float bv[4];
#pragma unroll
    for (int nr = 0; nr < 4; ++nr) bv[nr] = bias[n0 + wc * 64 + nr * 16 + l16];
    const float L2T  = 13.287712379549449f / 32.0f;   // log2(10000)/32
    const float inv0 = exp2f(-(float)l16 * L2T);
    const float inv1 = exp2f(-(float)(l16 + 16) * L2T);
#pragma unroll
    for (int mr = 0; mr < 4; ++mr)
#pragma unroll
      for (int r = 0; r < 4; ++r) {
        const int m = m0 + wr * 64 + mr * 16 + lg * 4 + r;
        const float t = ts[m];
        float s0, c0, s1, c1;
        sincosf(t * inv0, &s0, &c0);
        sincosf(t * inv1, &s1, &c1);
        const float p0 = acc[mr][0][r] + bv[0];
        const float p1 = acc[mr][1][r] + bv[1];
        const float p2 = acc[mr][2][r] + bv[2];
        const float p3 = acc[mr][3][r] + bv[3];
        const size_t base = (size_t)m * N + n0 + wc * 64 + l16;
        O[base + 0 ] = (_Float16)(p0 * c0 - p2 * s0);
        O[base + 16] = (_Float16)(p1 * c1 - p3 * s1);
        O[base + 32] = (_Float16)(p2 * c0 + p0 * s0);
        O[base + 48] = (_Float16)(p3 * c1 + p1 * s1);
      }
  }
}

// ---------------------------------------------------------------- causal flash attention
// Q,K : [S][DMODEL] f16 (post-RoPE) ; Vt : [DMODEL][S] f16 ; Om : [S][DMODEL] f16
__global__ __launch_bounds__(256)
void attn_fwd(const _Float16* __restrict__ Q,
              const _Float16* __restrict__ Km,
              const _Float16* __restrict__ Vt,
              _Float16* __restrict__ Om)
{
  __shared__ _Float16 p_lds[4][16][80];   // per-wave P transpose buffer (pitch 80 = 160B)
  const int tid  = threadIdx.x;
  const int wid  = tid >> 6, lane = tid & 63;
  const int l16  = lane & 15, lg = lane >> 4;
  const int q0   = blockIdx.x * 64 + wid * 16;
  const int h    = blockIdx.y;

  const size_t qoff = (size_t)(q0 + l16) * DMODEL + h * HDIM + lg * 8;
  const f16x8 qf0 = *(const f16x8*)&Q[qoff];
  const f16x8 qf1 = *(const f16x8*)&Q[qoff + 32];

  f32x4 acc[4] = {};
  float mreg[4], lsum[4] = {0.f, 0.f, 0.f, 0.f};
#pragma unroll
  for (int r = 0; r < 4; ++r) mreg[r] = -3.0e38f;

  const int nkt = (q0 + 79) >> 6;          // 64-wide kv tiles covering kv <= q0+15
  for (int kt = 0; kt < nkt; ++kt) {
    const int kv0 = kt * 64;
    f32x4 s[4];
#pragma unroll
    for (int cf = 0; cf < 4; ++cf) {
      const size_t koff = (size_t)(kv0 + cf * 16 + l16) * DMODEL + h * HDIM + lg * 8;
      const f16x8 kf0 = *(const f16x8*)&Km[koff];
      const f16x8 kf1 = *(const f16x8*)&Km[koff + 32];
      f32x4 z = {0.f, 0.f, 0.f, 0.f};
      s[cf] = __builtin_amdgcn_mfma_f32_16x16x32_f16(qf0, kf0, z, 0, 0, 0);
      s[cf] = __builtin_amdgcn_mfma_f32_16x16x32_f16(qf1, kf1, s[cf], 0, 0, 0);
    }
    const bool domask = (kv0 + 63 > q0);
#pragma unroll
    for (int cf = 0; cf < 4; ++cf)
#pragma unroll
      for (int r = 0; r < 4; ++r) {
        float v = s[cf][r] * 0.125f;                       // 1/sqrt(64)
        if (domask && (kv0 + cf * 16 + l16 > q0 + lg * 4 + r)) v = -3.0e38f;
        s[cf][r] = v;
      }
    float rmax[4], rsum[4], scl[4];
#pragma unroll
    for (int r = 0; r < 4; ++r)
      rmax[r] = fmaxf(fmaxf(s[0][r], s[1][r]), fmaxf(s[2][r], s[3][r]));
#pragma unroll
    for (int off = 1; off < 16; off <<= 1)
#pragma unroll
      for (int r = 0; r < 4; ++r)
        rmax[r] = fmaxf(rmax[r], __shfl_xor(rmax[r], off));
#pragma unroll
    for (int r = 0; r < 4; ++r) {
      const float mn = fmaxf(mreg[r], rmax[r]);
      scl[r] = __expf(mreg[r] - mn);
      mreg[r] = mn;
      rsum[r] = 0.f;
    }
#pragma unroll
    for (int cf = 0; cf < 4; ++cf)
#pragma unroll
      for (int r = 0; r < 4; ++r) {
        const float p = __expf(s[cf][r] - mreg[r]);
        s[cf][r] = p;
        rsum[r] += p;
      }
#pragma unroll
    for (int off = 1; off < 16; off <<= 1)
#pragma unroll
      for (int r = 0; r < 4; ++r)
        rsum[r] += __shfl_xor(rsum[r], off);
#pragma unroll
    for (int r = 0; r < 4; ++r)
      lsum[r] = lsum[r] * scl[r] + rsum[r];
#pragma unroll
    for (int nr = 0; nr < 4; ++nr)
#pragma unroll
      for (int r = 0; r < 4; ++r)
        acc[nr][r] *= scl[r];
    // P (S-fragment layout) -> LDS -> A-fragment layout
#pragma unroll
    for (int cf = 0; cf < 4; ++cf)
#pragma unroll
      for (int r = 0; r < 4; ++r)
        p_lds[wid][lg * 4 + r][cf * 16 + l16] = (_Float16)s[cf][r];
    asm volatile("s_waitcnt lgkmcnt(0)" ::: "memory");
    const f16x8 pa0 = *(const f16x8*)&p_lds[wid][l16][lg * 8];
    const f16x8 pa1 = *(const f16x8*)&p_lds[wid][l16][32 + lg * 8];
#pragma unroll
    for (int nr = 0; nr < 4; ++nr) {
      const size_t voff = (size_t)(h * HDIM + nr * 16 + l16) * S_LEN + kv0 + lg * 8;
      const f16x8 vf0 = *(const f16x8*)&Vt[voff];
      const f16x8 vf1 = *(const f16x8*)&Vt[voff + 32];
      acc[nr] = __builtin_amdgcn_mfma_f32_16x16x32_f16(pa0, vf0, acc[nr], 0, 0, 0);
      acc[nr] = __builtin_amdgcn_mfma_f32_16x16x32_f16(pa1, vf1, acc[nr], 0, 0, 0);
    }
  }
  float inv[4];
#pragma unroll
  for (int r = 0; r < 4; ++r) inv[r] = 1.0f / lsum[r];
#pragma unroll
  for (int nr = 0; nr < 4; ++nr)
#pragma unroll
    for (int r = 0; r < 4; ++r)
      Om[(size_t)(q0 + lg * 4 + r) * DMODEL + h * HDIM + nr * 16 + l16] =
          (_Float16)(acc[nr][r] * inv[r]);
}

// ---------------------------------------------------------------- launch
extern "C" void kernel_launch(void* const* d_in, const int* in_sizes, int n_in,
                              void* d_out, int out_size, void* d_ws, size_t ws_size,
                              hipStream_t stream)
{
  const float* hs = (const float*)d_in[0];
  const float* ts = (const float*)d_in[1];
  const float* Wq = (const float*)d_in[2];
  const float* bq = (const float*)d_in[3];
  const float* Wk = (const float*)d_in[4];
  const float* bk = (const float*)d_in[5];
  const float* Wv = (const float*)d_in[6];
  const float* bv = (const float*)d_in[7];
  const float* Wo = (const float*)d_in[8];
  float* out = (float*)d_out;

  char* ws = (char*)d_ws;
  const size_t MB = 1024 * 1024;
  _Float16* hsb  = (_Float16*)(ws + 0 * MB);    // [S][D]   8MB
  _Float16* wqb  = (_Float16*)(ws + 8 * MB);    // [D][D]   2MB
  _Float16* wkb  = (_Float16*)(ws + 10 * MB);
  _Float16* wvb  = (_Float16*)(ws + 12 * MB);
  _Float16* wob  = (_Float16*)(ws + 14 * MB);
  _Float16* Qb   = (_Float16*)(ws + 16 * MB);   // [S][D]   8MB
  _Float16* Kb   = (_Float16*)(ws + 24 * MB);   // [S][D]   8MB
  _Float16* Vtb  = (_Float16*)(ws + 32 * MB);   // [D][S]   8MB (transposed)
  _Float16* attb = (_Float16*)(ws + 40 * MB);   // [S][D]   8MB

  cast_f32_f16_k<<<dim3(4096), dim3(256), 0, stream>>>(hs, hsb, S_LEN * DMODEL);
  cast_f32_f16_k<<<dim3(1024), dim3(256), 0, stream>>>(Wq, wqb, DMODEL * DMODEL);
  cast_f32_f16_k<<<dim3(1024), dim3(256), 0, stream>>>(Wk, wkb, DMODEL * DMODEL);
  cast_f32_f16_k<<<dim3(1024), dim3(256), 0, stream>>>(Wv, wvb, DMODEL * DMODEL);
  cast_f32_f16_k<<<dim3(1024), dim3(256), 0, stream>>>(Wo, wob, DMODEL * DMODEL);

  dim3 gg(DMODEL / 128, S_LEN / 128);   // (8, 32)
  gemm128<0><<<gg, dim3(256), 0, stream>>>(hsb, wqb, bq, ts, (void*)Qb,  S_LEN, DMODEL, DMODEL);
  gemm128<0><<<gg, dim3(256), 0, stream>>>(hsb, wkb, bk, ts, (void*)Kb,  S_LEN, DMODEL, DMODEL);
  gemm128<1><<<gg, dim3(256), 0, stream>>>(hsb, wvb, bv, nullptr, (void*)Vtb, S_LEN, DMODEL, DMODEL);

  attn_fwd<<<dim3(S_LEN / 64, NHEAD), dim3(256), 0, stream>>>(Qb, Kb, Vtb, attb);

  gemm128<2><<<gg, dim3(256), 0, stream>>>(attb, wob, nullptr, nullptr, (void*)out, S_LEN, DMODEL, DMODEL);
}

// Round 3
// 261.092 us; speedup vs baseline: 2.1708x; 2.1708x over previous
//
#include <hip/hip_runtime.h>

#define S_LEN  4096
#define DMODEL 1024
#define NHEAD  16
#define HDIM   64

typedef float    f32x4  __attribute__((ext_vector_type(4)));
typedef float    f32x16 __attribute__((ext_vector_type(16)));
typedef _Float16 f16x8  __attribute__((ext_vector_type(8)));
typedef _Float16 f16x4v __attribute__((ext_vector_type(4)));
typedef __fp16   fp16x2 __attribute__((ext_vector_type(2)));
typedef unsigned int u32;
typedef u32 u32x4 __attribute__((ext_vector_type(4)));

// ---------------------------------------------------------------- helpers
__device__ __forceinline__ void gl2lds16(const _Float16* g, _Float16* l) {
  // async global->LDS, 16B per lane, LDS dest = wave-uniform base + lane*16
  __builtin_amdgcn_global_load_lds(
      (const __attribute__((address_space(1))) unsigned int*)g,
      (__attribute__((address_space(3))) unsigned int*)l, 16, 0, 0);
}

__device__ __forceinline__ u32 pkrtz_u(float a, float b) {
  fp16x2 h = __builtin_amdgcn_cvt_pkrtz(a, b);
  return __builtin_bit_cast(u32, h);
}

// ---------------------------------------------------------------- cast f32 -> f16
__global__ void cast_f32_f16_k(const float* __restrict__ in,
                               _Float16* __restrict__ out, int n) {
  int i = (blockIdx.x * blockDim.x + threadIdx.x) * 4;
  if (i + 3 < n) {
    const float4 v = *(const float4*)(in + i);
    f16x4v o = { (_Float16)v.x, (_Float16)v.y, (_Float16)v.z, (_Float16)v.w };
    *(f16x4v*)(out + i) = o;
  }
}

// ---------------------------------------------------------------- GEMM  y = A @ W^T (+bias) (+RoPE)
// (unchanged from round 1 — correct, ~25us each; revisit after attention)
template<int MODE>
__global__ __launch_bounds__(256)
void gemm128(const _Float16* __restrict__ A,
             const _Float16* __restrict__ Bw,
             const float* __restrict__ bias,
             const float* __restrict__ ts,
             void* __restrict__ outp,
             int M, int N, int K)
{
  __shared__ _Float16 lA[128 * 64];
  __shared__ _Float16 lB[128 * 64];

  const int tid  = threadIdx.x;
  const int wid  = tid >> 6;
  const int lane = tid & 63;
  const int l16  = lane & 15;
  const int lg   = lane >> 4;
  const int wr = wid >> 1, wc = wid & 1;
  const int m0 = blockIdx.y * 128, n0 = blockIdx.x * 128;

  const int lrow   = lane >> 3;
  const int gchunk = (lane & 7) ^ lrow;

  f32x4 acc[4][4] = {};

  for (int k0 = 0; k0 < K; k0 += 64) {
#pragma unroll
    for (int it = 0; it < 4; ++it) {
      const int rbase = (it * 4 + wid) * 8;
      gl2lds16(A  + (size_t)(m0 + rbase + lrow) * K + k0 + gchunk * 8, &lA[rbase * 64]);
      gl2lds16(Bw + (size_t)(n0 + rbase + lrow) * K + k0 + gchunk * 8, &lB[rbase * 64]);
    }
    __syncthreads();
#pragma unroll
    for (int kk = 0; kk < 2; ++kk) {
      f16x8 af[4], bfr[4];
#pragma unroll
      for (int mr = 0; mr < 4; ++mr) {
        const int row = wr * 64 + mr * 16 + l16;
        const int ch  = (kk * 4 + lg) ^ (l16 & 7);
        af[mr] = *(const f16x8*)&lA[row * 64 + ch * 8];
      }
#pragma unroll
      for (int nr = 0; nr < 4; ++nr) {
        const int row = wc * 64 + nr * 16 + l16;
        const int ch  = (kk * 4 + lg) ^ (l16 & 7);
        bfr[nr] = *(const f16x8*)&lB[row * 64 + ch * 8];
      }
#pragma unroll
      for (int mr = 0; mr < 4; ++mr)
#pragma unroll
        for (int nr = 0; nr < 4; ++nr)
          acc[mr][nr] = __builtin_amdgcn_mfma_f32_16x16x32_f16(af[mr], bfr[nr], acc[mr][nr], 0, 0, 0);
    }
    __syncthreads();
  }

  if (MODE == 2) {
    float* O = (float*)outp;
#pragma unroll
    for (int mr = 0; mr < 4; ++mr)
#pragma unroll
      for (int r = 0; r < 4; ++r) {
        const int m = m0 + wr * 64 + mr * 16 + lg * 4 + r;
#pragma unroll
        for (int nr = 0; nr < 4; ++nr) {
          const int n = n0 + wc * 64 + nr * 16 + l16;
          O[(size_t)m * N + n] = acc[mr][nr][r];
        }
      }
  } else if (MODE == 1) {
    _Float16* O = (_Float16*)outp;   // [N][M] transposed V
    float bv[4];
#pragma unroll
    for (int nr = 0; nr < 4; ++nr) bv[nr] = bias[n0 + wc * 64 + nr * 16 + l16];
#pragma unroll
    for (int mr = 0; mr < 4; ++mr) {
      const int mbase = m0 + wr * 64 + mr * 16 + lg * 4;
#pragma unroll
      for (int nr = 0; nr < 4; ++nr) {
        const int n = n0 + wc * 64 + nr * 16 + l16;
        f16x4v o = { (_Float16)(acc[mr][nr][0] + bv[nr]),
                     (_Float16)(acc[mr][nr][1] + bv[nr]),
                     (_Float16)(acc[mr][nr][2] + bv[nr]),
                     (_Float16)(acc[mr][nr][3] + bv[nr]) };
        *(f16x4v*)&O[(size_t)n * M + mbase] = o;
      }
    }
  } else { // MODE 0: bias + CT-RoPE, f16 out [M][N]
    _Float16* O = (_Float16*)outp;
    float bv[4];
#pragma unroll
    for (int nr = 0; nr < 4; ++nr) bv[nr] = bias[n0 + wc * 64 + nr * 16 + l16];
    const float L2T  = 13.287712379549449f / 32.0f;
    const float inv0 = exp2f(-(float)l16 * L2T);
    const float inv1 = exp2f(-(float)(l16 + 16) * L2T);
#pragma unroll
    for (int mr = 0; mr < 4; ++mr)
#pragma unroll
      for (int r = 0; r < 4; ++r) {
        const int m = m0 + wr * 64 + mr * 16 + lg * 4 + r;
        const float t = ts[m];
        float s0, c0, s1, c1;
        sincosf(t * inv0, &s0, &c0);
        sincosf(t * inv1, &s1, &c1);
        const float p0 = acc[mr][0][r] + bv[0];
        const float p1 = acc[mr][1][r] + bv[1];
        const float p2 = acc[mr][2][r] + bv[2];
        const float p3 = acc[mr][3][r] + bv[3];
        const size_t base = (size_t)m * N + n0 + wc * 64 + l16;
        O[base + 0 ] = (_Float16)(p0 * c0 - p2 * s0);
        O[base + 16] = (_Float16)(p1 * c1 - p3 * s1);
        O[base + 32] = (_Float16)(p2 * c0 + p0 * s0);
        O[base + 48] = (_Float16)(p3 * c1 + p1 * s1);
      }
  }
}

// ---------------------------------------------------------------- flash attention v2
// Swapped QK^T (S^T via mfma(K,Q)) + in-register softmax + cvt_pk/shfl exchange
// for PV B-frags. K/V tiles staged to LDS (shared by 4 waves), double-buffered,
// XOR-swizzled (slot ^= (row>>2)&7) for conflict-free ds_read_b128.
// Block: 256 thr = 4 waves, 128 q-rows/block, 32 q-rows/wave (32x32x16 MFMA).
__device__ __forceinline__ void stage_tiles(const _Float16* __restrict__ Km,
                                            const _Float16* __restrict__ Vt,
                                            _Float16* kdst, _Float16* vdst,
                                            int kv0, int h, int wid, int lane) {
#pragma unroll
  for (int j = 0; j < 2; ++j) {
    const int rb  = wid * 16 + j * 8;        // wave-uniform row base
    const int row = rb + (lane >> 3);
    const int g   = (lane & 7) ^ ((row >> 2) & 7);  // pre-swizzled source col8
    gl2lds16(Km + (size_t)(kv0 + row) * DMODEL + h * HDIM + g * 8, kdst + rb * 64);
    gl2lds16(Vt + (size_t)(h * HDIM + row) * S_LEN + kv0 + g * 8, vdst + rb * 64);
  }
}

__global__ __launch_bounds__(256)
void attn_fwd(const _Float16* __restrict__ Q,
              const _Float16* __restrict__ Km,
              const _Float16* __restrict__ Vt,
              _Float16* __restrict__ Om)
{
  __shared__ __align__(16) _Float16 smem[2][2][64 * 64];   // [buf][K|V][64x64], 32KB

  const int tid  = threadIdx.x;
  const int wid  = tid >> 6, lane = tid & 63;
  const int l31  = lane & 31;
  const bool hi  = (lane & 32) != 0;
  // XCD-aware mapping: hw assigns block d -> XCD d%8; give each XCD 2 heads.
  const int flat = blockIdx.x, xcd = flat & 7, sub = flat >> 3;
  const int h    = xcd * 2 + (sub >> 5);
  const int q0blk = (sub & 31) * 128;
  const int q0w   = q0blk + wid * 32;
  const int lastkt = (q0w + 31) >> 6;        // wave's diagonal tile
  const int nkt    = (q0blk >> 6) + 2;       // block's tile count
  const int sw     = (l31 >> 2) & 7;         // LDS read swizzle

  // Q B-fragments (pre-scaled by 1/sqrt(64) * log2(e) for exp2-domain softmax)
  f16x8 qf[4];
  {
    const float qs = 0.18033688f;
    const size_t qbase = (size_t)(q0w + l31) * DMODEL + h * HDIM + (hi ? 8 : 0);
#pragma unroll
    for (int ks = 0; ks < 4; ++ks) {
      f16x8 t = *(const f16x8*)&Q[qbase + ks * 16];
#pragma unroll
      for (int e = 0; e < 8; ++e) qf[ks][e] = (_Float16)((float)t[e] * qs);
    }
  }

  f32x16 acc0, acc1;
#pragma unroll
  for (int r = 0; r < 16; ++r) { acc0[r] = 0.f; acc1[r] = 0.f; }
  float m_run = -1e30f, l_run = 0.f;

  stage_tiles(Km, Vt, &smem[0][0][0], &smem[0][1][0], 0, h, wid, lane);
  __syncthreads();
  int cur = 0;

  for (int kt = 0; kt < nkt; ++kt) {
    if (kt + 1 < nkt)
      stage_tiles(Km, Vt, &smem[cur ^ 1][0][0], &smem[cur ^ 1][1][0],
                  (kt + 1) * 64, h, wid, lane);

    if (kt <= lastkt) {
      const _Float16* kb = &smem[cur][0][0];
      const _Float16* vb = &smem[cur][1][0];

      // ---- S^T = K . Q^T  (rows = kv, cols = q)
      f32x16 s0, s1;
#pragma unroll
      for (int r = 0; r < 16; ++r) { s0[r] = 0.f; s1[r] = 0.f; }
#pragma unroll
      for (int ks = 0; ks < 4; ++ks) {
        const int cs = ((ks * 2 + (hi ? 1 : 0)) ^ sw) * 8;
        const f16x8 ka0 = *(const f16x8*)&kb[l31 * 64 + cs];
        const f16x8 ka1 = *(const f16x8*)&kb[(32 + l31) * 64 + cs];
        s0 = __builtin_amdgcn_mfma_f32_32x32x16_f16(ka0, qf[ks], s0, 0, 0, 0);
        s1 = __builtin_amdgcn_mfma_f32_32x32x16_f16(ka1, qf[ks], s1, 0, 0, 0);
      }

      const int kv0 = kt * 64;
      if (kt == lastkt) {            // causal mask: only the diagonal tile
        const int q = q0w + l31;
#pragma unroll
        for (int r = 0; r < 16; ++r) {
          const int kvr = kv0 + (r & 3) + 8 * (r >> 2) + (hi ? 4 : 0);
          if (kvr > q)      s0[r] = -1e30f;
          if (kvr + 32 > q) s1[r] = -1e30f;
        }
      }

      // ---- online softmax (exp2 domain), row = q = lane&31, lane-local
      float t8[8];
#pragma unroll
      for (int p = 0; p < 8; ++p)
        t8[p] = fmaxf(fmaxf(s0[2*p], s0[2*p+1]), fmaxf(s1[2*p], s1[2*p+1]));
      float pm = fmaxf(fmaxf(fmaxf(t8[0], t8[1]), fmaxf(t8[2], t8[3])),
                       fmaxf(fmaxf(t8[4], t8[5]), fmaxf(t8[6], t8[7])));
      pm = fmaxf(pm, __shfl_xor(pm, 32));
      const float mn  = fmaxf(m_run, pm);
      const float scl = exp2f(m_run - mn);
      m_run = mn;

      float sa = 0.f, sb = 0.f, sc = 0.f, sd = 0.f;
#pragma unroll
      for (int r = 0; r < 16; r += 2) {
        s0[r]   = exp2f(s0[r]   - mn);
        s0[r+1] = exp2f(s0[r+1] - mn);
        s1[r]   = exp2f(s1[r]   - mn);
        s1[r+1] = exp2f(s1[r+1] - mn);
        sa += s0[r]; sb += s0[r+1]; sc += s1[r]; sd += s1[r+1];
      }
      float rsum = (sa + sb) + (sc + sd);
      rsum += __shfl_xor(rsum, 32);
      l_run = l_run * scl + rsum;
#pragma unroll
      for (int r = 0; r < 16; ++r) { acc0[r] *= scl; acc1[r] *= scl; }

      // ---- P^T (f32) -> packed f16 pairs
      u32 pk[2][8];
#pragma unroll
      for (int p = 0; p < 8; ++p) {
        pk[0][p] = pkrtz_u(s0[2*p], s0[2*p+1]);
        pk[1][p] = pkrtz_u(s1[2*p], s1[2*p+1]);
      }

      // ---- out^T += Vt . P^T   (A = V tile rows d, B = P^T built in-register)
#pragma unroll
      for (int ks = 0; ks < 4; ++ks) {
        const int c = ks >> 1, base = (ks & 1) * 4;
        const u32 own0 = hi ? pk[c][base+2] : pk[c][base+0];
        const u32 own1 = hi ? pk[c][base+3] : pk[c][base+1];
        const u32 opp0 = hi ? pk[c][base+0] : pk[c][base+2];
        const u32 opp1 = hi ? pk[c][base+1] : pk[c][base+3];
        const u32 sh0 = (u32)__shfl_xor((int)opp0, 32);
        const u32 sh1 = (u32)__shfl_xor((int)opp1, 32);
        u32x4 bw;
        bw[0] = hi ? sh0 : own0;   // k 0..1 within half-step (from half 0)
        bw[1] = hi ? sh1 : own1;   // k 2..3
        bw[2] = hi ? own0 : sh0;   // k 4..5 (from half 1)
        bw[3] = hi ? own1 : sh1;   // k 6..7
        const f16x8 pb = __builtin_bit_cast(f16x8, bw);
        const int cs = ((ks * 2 + (hi ? 1 : 0)) ^ sw) * 8;
        const f16x8 va0 = *(const f16x8*)&vb[l31 * 64 + cs];
        const f16x8 va1 = *(const f16x8*)&vb[(32 + l31) * 64 + cs];
        acc0 = __builtin_amdgcn_mfma_f32_32x32x16_f16(va0, pb, acc0, 0, 0, 0);
        acc1 = __builtin_amdgcn_mfma_f32_32x32x16_f16(va1, pb, acc1, 0, 0, 0);
      }
    }
    __syncthreads();
    cur ^= 1;
  }

  // ---- epilogue: out^T -> LDS transpose (padded rows) -> coalesced store
  _Float16* tr = &smem[0][0][0] + wid * 2304;     // 32 rows x 72 (144B, 16B-aligned)
  const float invl = 1.0f / l_run;
#pragma unroll
  for (int r = 0; r < 16; ++r) {
    const int d = (r & 3) + 8 * (r >> 2) + (hi ? 4 : 0);
    tr[l31 * 72 + d]      = (_Float16)(acc0[r] * invl);
    tr[l31 * 72 + 32 + d] = (_Float16)(acc1[r] * invl);
  }
  __syncthreads();
#pragma unroll
  for (int cc = 0; cc < 4; ++cc) {
    const int qq = cc * 8 + (lane >> 3), c8 = lane & 7;
    const f16x8 v = *(const f16x8*)&tr[qq * 72 + c8 * 8];
    *(f16x8*)&Om[(size_t)(q0w + qq) * DMODEL + h * HDIM + c8 * 8] = v;
  }
}

// ---------------------------------------------------------------- launch
extern "C" void kernel_launch(void* const* d_in, const int* in_sizes, int n_in,
                              void* d_out, int out_size, void* d_ws, size_t ws_size,
                              hipStream_t stream)
{
  const float* hs = (const float*)d_in[0];
  const float* ts = (const float*)d_in[1];
  const float* Wq = (const float*)d_in[2];
  const float* bq = (const float*)d_in[3];
  const float* Wk = (const float*)d_in[4];
  const float* bk = (const float*)d_in[5];
  const float* Wv = (const float*)d_in[6];
  const float* bv = (const float*)d_in[7];
  const float* Wo = (const float*)d_in[8];
  float* out = (float*)d_out;

  char* ws = (char*)d_ws;
  const size_t MB = 1024 * 1024;
  _Float16* hsb  = (_Float16*)(ws + 0 * MB);
  _Float16* wqb  = (_Float16*)(ws + 8 * MB);
  _Float16* wkb  = (_Float16*)(ws + 10 * MB);
  _Float16* wvb  = (_Float16*)(ws + 12 * MB);
  _Float16* wob  = (_Float16*)(ws + 14 * MB);
  _Float16* Qb   = (_Float16*)(ws + 16 * MB);
  _Float16* Kb   = (_Float16*)(ws + 24 * MB);
  _Float16* Vtb  = (_Float16*)(ws + 32 * MB);   // [D][S] transposed
  _Float16* attb = (_Float16*)(ws + 40 * MB);

  cast_f32_f16_k<<<dim3(4096), dim3(256), 0, stream>>>(hs, hsb, S_LEN * DMODEL);
  cast_f32_f16_k<<<dim3(1024), dim3(256), 0, stream>>>(Wq, wqb, DMODEL * DMODEL);
  cast_f32_f16_k<<<dim3(1024), dim3(256), 0, stream>>>(Wk, wkb, DMODEL * DMODEL);
  cast_f32_f16_k<<<dim3(1024), dim3(256), 0, stream>>>(Wv, wvb, DMODEL * DMODEL);
  cast_f32_f16_k<<<dim3(1024), dim3(256), 0, stream>>>(Wo, wob, DMODEL * DMODEL);

  dim3 gg(DMODEL / 128, S_LEN / 128);
  gemm128<0><<<gg, dim3(256), 0, stream>>>(hsb, wqb, bq, ts, (void*)Qb,  S_LEN, DMODEL, DMODEL);
  gemm128<0><<<gg, dim3(256), 0, stream>>>(hsb, wkb, bk, ts, (void*)Kb,  S_LEN, DMODEL, DMODEL);
  gemm128<1><<<gg, dim3(256), 0, stream>>>(hsb, wvb, bv, nullptr, (void*)Vtb, S_LEN, DMODEL, DMODEL);

  attn_fwd<<<dim3((S_LEN / 128) * NHEAD), dim3(256), 0, stream>>>(Qb, Kb, Vtb, attb);

  gemm128<2><<<gg, dim3(256), 0, stream>>>(attb, wob, nullptr, nullptr, (void*)out, S_LEN, DMODEL, DMODEL);
}

// Round 4
// 192.988 us; speedup vs baseline: 2.9368x; 1.3529x over previous
//
#include <hip/hip_runtime.h>

#define S_LEN  4096
#define DMODEL 1024
#define NHEAD  16
#define HDIM   64

typedef float    f32x4  __attribute__((ext_vector_type(4)));
typedef float    f32x16 __attribute__((ext_vector_type(16)));
typedef _Float16 f16x8  __attribute__((ext_vector_type(8)));
typedef _Float16 f16x4v __attribute__((ext_vector_type(4)));
typedef __fp16   fp16x2 __attribute__((ext_vector_type(2)));
typedef unsigned int u32;
typedef u32 u32x4 __attribute__((ext_vector_type(4)));

// ---------------------------------------------------------------- helpers
__device__ __forceinline__ void gl2lds16(const _Float16* g, _Float16* l) {
  // async global->LDS, 16B per lane, LDS dest = wave-uniform base + lane*16
  __builtin_amdgcn_global_load_lds(
      (const __attribute__((address_space(1))) unsigned int*)g,
      (__attribute__((address_space(3))) unsigned int*)l, 16, 0, 0);
}

__device__ __forceinline__ u32 pkrtz_u(float a, float b) {
  fp16x2 h = __builtin_amdgcn_cvt_pkrtz(a, b);
  return __builtin_bit_cast(u32, h);
}

// ---------------------------------------------------------------- casts
__global__ void cast_f32_f16_k(const float* __restrict__ in,
                               _Float16* __restrict__ out, int n) {
  int i = (blockIdx.x * blockDim.x + threadIdx.x) * 4;
  if (i + 3 < n) {
    const float4 v = *(const float4*)(in + i);
    f16x4v o = { (_Float16)v.x, (_Float16)v.y, (_Float16)v.z, (_Float16)v.w };
    *(f16x4v*)(out + i) = o;
  }
}

// 4 weight matrices (1M elems each) in one launch
__global__ void cast4_k(const float* __restrict__ a, const float* __restrict__ b,
                        const float* __restrict__ c, const float* __restrict__ d,
                        _Float16* __restrict__ oa, _Float16* __restrict__ ob,
                        _Float16* __restrict__ oc, _Float16* __restrict__ od) {
  const int seg = blockIdx.y;
  const float* in = seg == 0 ? a : seg == 1 ? b : seg == 2 ? c : d;
  _Float16*   out = seg == 0 ? oa : seg == 1 ? ob : seg == 2 ? oc : od;
  const int i = (blockIdx.x * blockDim.x + threadIdx.x) * 4;
  const float4 v = *(const float4*)(in + i);
  f16x4v o = { (_Float16)v.x, (_Float16)v.y, (_Float16)v.z, (_Float16)v.w };
  *(f16x4v*)(out + i) = o;
}

// ---------------------------------------------------------------- fused QKV GEMM
// A: [4096][1024] f16.  Bw: [3072][1024] f16 (Wq|Wk|Wv rows concatenated).
// n0 <  1024 : Q -> Qb [S][D] + bias + CT-RoPE
// n0 <  2048 : K -> Kb [S][D] + bias + CT-RoPE
// n0 >= 2048 : V -> Vtb [D][S] transposed + bias
__global__ __launch_bounds__(256)
void gemm_qkv(const _Float16* __restrict__ A,
              const _Float16* __restrict__ Bw,
              const float* __restrict__ bq,
              const float* __restrict__ bk,
              const float* __restrict__ bv,
              const float* __restrict__ ts,
              _Float16* __restrict__ Qb,
              _Float16* __restrict__ Kb,
              _Float16* __restrict__ Vtb)
{
  __shared__ _Float16 lA[128 * 64];
  __shared__ _Float16 lB[128 * 64];

  const int tid  = threadIdx.x;
  const int wid  = tid >> 6;
  const int lane = tid & 63;
  const int l16  = lane & 15;
  const int lg   = lane >> 4;
  const int wr = wid >> 1, wc = wid & 1;
  const int m0 = blockIdx.y * 128, n0 = blockIdx.x * 128;
  const int K = DMODEL, M = S_LEN;

  const int lrow   = lane >> 3;
  const int gchunk = (lane & 7) ^ lrow;

  f32x4 acc[4][4] = {};

  for (int k0 = 0; k0 < K; k0 += 64) {
#pragma unroll
    for (int it = 0; it < 4; ++it) {
      const int rbase = (it * 4 + wid) * 8;
      gl2lds16(A  + (size_t)(m0 + rbase + lrow) * K + k0 + gchunk * 8, &lA[rbase * 64]);
      gl2lds16(Bw + (size_t)(n0 + rbase + lrow) * K + k0 + gchunk * 8, &lB[rbase * 64]);
    }
    __syncthreads();
#pragma unroll
    for (int kk = 0; kk < 2; ++kk) {
      f16x8 af[4], bfr[4];
#pragma unroll
      for (int mr = 0; mr < 4; ++mr) {
        const int row = wr * 64 + mr * 16 + l16;
        const int ch  = (kk * 4 + lg) ^ (l16 & 7);
        af[mr] = *(const f16x8*)&lA[row * 64 + ch * 8];
      }
#pragma unroll
      for (int nr = 0; nr < 4; ++nr) {
        const int row = wc * 64 + nr * 16 + l16;
        const int ch  = (kk * 4 + lg) ^ (l16 & 7);
        bfr[nr] = *(const f16x8*)&lB[row * 64 + ch * 8];
      }
#pragma unroll
      for (int mr = 0; mr < 4; ++mr)
#pragma unroll
        for (int nr = 0; nr < 4; ++nr)
          acc[mr][nr] = __builtin_amdgcn_mfma_f32_16x16x32_f16(af[mr], bfr[nr], acc[mr][nr], 0, 0, 0);
    }
    __syncthreads();
  }

  if (n0 >= 2048) {           // ---- V: bias + transposed store
    const int dbase = n0 - 2048;
    float bvv[4];
#pragma unroll
    for (int nr = 0; nr < 4; ++nr) bvv[nr] = bv[dbase + wc * 64 + nr * 16 + l16];
#pragma unroll
    for (int mr = 0; mr < 4; ++mr) {
      const int mbase = m0 + wr * 64 + mr * 16 + lg * 4;
#pragma unroll
      for (int nr = 0; nr < 4; ++nr) {
        const int d = dbase + wc * 64 + nr * 16 + l16;
        f16x4v o = { (_Float16)(acc[mr][nr][0] + bvv[nr]),
                     (_Float16)(acc[mr][nr][1] + bvv[nr]),
                     (_Float16)(acc[mr][nr][2] + bvv[nr]),
                     (_Float16)(acc[mr][nr][3] + bvv[nr]) };
        *(f16x4v*)&Vtb[(size_t)d * M + mbase] = o;
      }
    }
  } else {                    // ---- Q or K: bias + CT-RoPE
    _Float16* O = (n0 < 1024) ? Qb : Kb;
    const float* bias = (n0 < 1024) ? bq : bk;
    const int nloc = n0 & 1023;
    float bvv[4];
#pragma unroll
    for (int nr = 0; nr < 4; ++nr) bvv[nr] = bias[nloc + wc * 64 + nr * 16 + l16];
    const float L2T  = 13.287712379549449f / 32.0f;   // log2(10000)/32
    const float inv0 = exp2f(-(float)l16 * L2T);
    const float inv1 = exp2f(-(float)(l16 + 16) * L2T);
#pragma unroll
    for (int mr = 0; mr < 4; ++mr)
#pragma unroll
      for (int r = 0; r < 4; ++r) {
        const int m = m0 + wr * 64 + mr * 16 + lg * 4 + r;
        const float t = ts[m];
        float s0, c0, s1, c1;
        sincosf(t * inv0, &s0, &c0);
        sincosf(t * inv1, &s1, &c1);
        const float p0 = acc[mr][0][r] + bvv[0];
        const float p1 = acc[mr][1][r] + bvv[1];
        const float p2 = acc[mr][2][r] + bvv[2];
        const float p3 = acc[mr][3][r] + bvv[3];
        const size_t base = (size_t)m * DMODEL + nloc + wc * 64 + l16;
        O[base + 0 ] = (_Float16)(p0 * c0 - p2 * s0);
        O[base + 16] = (_Float16)(p1 * c1 - p3 * s1);
        O[base + 32] = (_Float16)(p2 * c0 + p0 * s0);
        O[base + 48] = (_Float16)(p3 * c1 + p1 * s1);
      }
  }
}

// ---------------------------------------------------------------- O-proj GEMM (f32 out)
__global__ __launch_bounds__(256)
void gemm_o(const _Float16* __restrict__ A,
            const _Float16* __restrict__ Bw,
            float* __restrict__ O)
{
  __shared__ _Float16 lA[128 * 64];
  __shared__ _Float16 lB[128 * 64];

  const int tid  = threadIdx.x;
  const int wid  = tid >> 6;
  const int lane = tid & 63;
  const int l16  = lane & 15;
  const int lg   = lane >> 4;
  const int wr = wid >> 1, wc = wid & 1;
  const int m0 = blockIdx.y * 128, n0 = blockIdx.x * 128;
  const int K = DMODEL, N = DMODEL;

  const int lrow   = lane >> 3;
  const int gchunk = (lane & 7) ^ lrow;

  f32x4 acc[4][4] = {};

  for (int k0 = 0; k0 < K; k0 += 64) {
#pragma unroll
    for (int it = 0; it < 4; ++it) {
      const int rbase = (it * 4 + wid) * 8;
      gl2lds16(A  + (size_t)(m0 + rbase + lrow) * K + k0 + gchunk * 8, &lA[rbase * 64]);
      gl2lds16(Bw + (size_t)(n0 + rbase + lrow) * K + k0 + gchunk * 8, &lB[rbase * 64]);
    }
    __syncthreads();
#pragma unroll
    for (int kk = 0; kk < 2; ++kk) {
      f16x8 af[4], bfr[4];
#pragma unroll
      for (int mr = 0; mr < 4; ++mr) {
        const int row = wr * 64 + mr * 16 + l16;
        const int ch  = (kk * 4 + lg) ^ (l16 & 7);
        af[mr] = *(const f16x8*)&lA[row * 64 + ch * 8];
      }
#pragma unroll
      for (int nr = 0; nr < 4; ++nr) {
        const int row = wc * 64 + nr * 16 + l16;
        const int ch  = (kk * 4 + lg) ^ (l16 & 7);
        bfr[nr] = *(const f16x8*)&lB[row * 64 + ch * 8];
      }
#pragma unroll
      for (int mr = 0; mr < 4; ++mr)
#pragma unroll
        for (int nr = 0; nr < 4; ++nr)
          acc[mr][nr] = __builtin_amdgcn_mfma_f32_16x16x32_f16(af[mr], bfr[nr], acc[mr][nr], 0, 0, 0);
    }
    __syncthreads();
  }

#pragma unroll
  for (int mr = 0; mr < 4; ++mr)
#pragma unroll
    for (int r = 0; r < 4; ++r) {
      const int m = m0 + wr * 64 + mr * 16 + lg * 4 + r;
#pragma unroll
      for (int nr = 0; nr < 4; ++nr) {
        const int n = n0 + wc * 64 + nr * 16 + l16;
        O[(size_t)m * N + n] = acc[mr][nr][r];
      }
    }
}

// ---------------------------------------------------------------- flash attention v3
// 1024 blocks x 128 threads (2 waves, 64 q-rows/block, 32 q/wave).
// LPT dispatch: heaviest q-blocks first, heads interleaved, XCD-paired.
// LDS K/V double-buffered, XOR swizzle slot^=(row&7) -> conflict-free b128.
__device__ __forceinline__ void stage_tiles(const _Float16* __restrict__ Km,
                                            const _Float16* __restrict__ Vt,
                                            _Float16* kdst, _Float16* vdst,
                                            int kv0, int h, int wid, int lane) {
#pragma unroll
  for (int j8 = 0; j8 < 4; ++j8) {
    const int rb  = wid * 32 + j8 * 8;       // wave-uniform row base
    const int row = rb + (lane >> 3);
    const int g   = (lane & 7) ^ (row & 7);  // pre-swizzled source chunk
    gl2lds16(Km + (size_t)(kv0 + row) * DMODEL + h * HDIM + g * 8, kdst + rb * 64);
    gl2lds16(Vt + (size_t)(h * HDIM + row) * S_LEN + kv0 + g * 8, vdst + rb * 64);
  }
}

__global__ __launch_bounds__(128)
void attn_fwd(const _Float16* __restrict__ Q,
              const _Float16* __restrict__ Km,
              const _Float16* __restrict__ Vt,
              _Float16* __restrict__ Om)
{
  __shared__ __align__(16) _Float16 smem[2][2][64 * 64];   // 32KB

  const int tid  = threadIdx.x;
  const int wid  = tid >> 6, lane = tid & 63;
  const int l31  = lane & 31;
  const bool hi  = (lane & 32) != 0;
  // LPT + XCD mapping: flat&7 -> XCD; j descending (heaviest first); heads interleaved.
  const int flat = blockIdx.x, xcd = flat & 7, sub = flat >> 3;   // sub 0..127
  const int j    = 63 - (sub >> 1);
  const int h    = xcd * 2 + (sub & 1);
  const int q0w  = j * 64 + wid * 32;
  const int nkt  = j + 1;
  const int sw   = l31 & 7;                  // LDS read swizzle (row&7)

  // Q B-fragments, pre-scaled by (1/sqrt(64))*log2(e)
  f16x8 qf[4];
  {
    const float qs = 0.18033688f;
    const size_t qbase = (size_t)(q0w + l31) * DMODEL + h * HDIM + (hi ? 8 : 0);
#pragma unroll
    for (int ks = 0; ks < 4; ++ks) {
      f16x8 t = *(const f16x8*)&Q[qbase + ks * 16];
#pragma unroll
      for (int e = 0; e < 8; ++e) qf[ks][e] = (_Float16)((float)t[e] * qs);
    }
  }

  f32x16 acc0, acc1;
#pragma unroll
  for (int r = 0; r < 16; ++r) { acc0[r] = 0.f; acc1[r] = 0.f; }
  float m_run = -1e30f, l_run = 0.f;

  stage_tiles(Km, Vt, &smem[0][0][0], &smem[0][1][0], 0, h, wid, lane);
  __syncthreads();
  int cur = 0;

  for (int kt = 0; kt < nkt; ++kt) {
    if (kt + 1 < nkt)
      stage_tiles(Km, Vt, &smem[cur ^ 1][0][0], &smem[cur ^ 1][1][0],
                  (kt + 1) * 64, h, wid, lane);

    const _Float16* kb = &smem[cur][0][0];
    const _Float16* vb = &smem[cur][1][0];

    // ---- S^T = K . Q^T  (rows = kv, cols = q)
    f32x16 s0, s1;
#pragma unroll
    for (int r = 0; r < 16; ++r) { s0[r] = 0.f; s1[r] = 0.f; }
#pragma unroll
    for (int ks = 0; ks < 4; ++ks) {
      const int cs = ((ks * 2 + (hi ? 1 : 0)) ^ sw) * 8;
      const f16x8 ka0 = *(const f16x8*)&kb[l31 * 64 + cs];
      const f16x8 ka1 = *(const f16x8*)&kb[(32 + l31) * 64 + cs];
      s0 = __builtin_amdgcn_mfma_f32_32x32x16_f16(ka0, qf[ks], s0, 0, 0, 0);
      s1 = __builtin_amdgcn_mfma_f32_32x32x16_f16(ka1, qf[ks], s1, 0, 0, 0);
    }

    if (kt == nkt - 1) {           // diagonal tile: causal mask
      const int kv0 = kt * 64, q = q0w + l31;
#pragma unroll
      for (int r = 0; r < 16; ++r) {
        const int kvr = kv0 + (r & 3) + 8 * (r >> 2) + (hi ? 4 : 0);
        if (kvr > q)      s0[r] = -1e30f;
        if (kvr + 32 > q) s1[r] = -1e30f;
      }
    }

    // ---- online softmax (exp2 domain), lane-local rows, defer-max (T13)
    float t8[8];
#pragma unroll
    for (int p = 0; p < 8; ++p)
      t8[p] = fmaxf(fmaxf(s0[2*p], s0[2*p+1]), fmaxf(s1[2*p], s1[2*p+1]));
    float pm = fmaxf(fmaxf(fmaxf(t8[0], t8[1]), fmaxf(t8[2], t8[3])),
                     fmaxf(fmaxf(t8[4], t8[5]), fmaxf(t8[6], t8[7])));
    pm = fmaxf(pm, __shfl_xor(pm, 32));

    if (!__all(pm <= m_run + 10.f)) {
      const float mn  = fmaxf(m_run, pm);
      const float scl = exp2f(m_run - mn);
      m_run = mn;
      l_run *= scl;
#pragma unroll
      for (int r = 0; r < 16; ++r) { acc0[r] *= scl; acc1[r] *= scl; }
    }

    float sa = 0.f, sb = 0.f, sc = 0.f, sd = 0.f;
#pragma unroll
    for (int r = 0; r < 16; r += 2) {
      s0[r]   = exp2f(s0[r]   - m_run);
      s0[r+1] = exp2f(s0[r+1] - m_run);
      s1[r]   = exp2f(s1[r]   - m_run);
      s1[r+1] = exp2f(s1[r+1] - m_run);
      sa += s0[r]; sb += s0[r+1]; sc += s1[r]; sd += s1[r+1];
    }
    float rsum = (sa + sb) + (sc + sd);
    rsum += __shfl_xor(rsum, 32);
    l_run += rsum;

    // ---- P^T -> packed f16 pairs
    u32 pk[2][8];
#pragma unroll
    for (int p = 0; p < 8; ++p) {
      pk[0][p] = pkrtz_u(s0[2*p], s0[2*p+1]);
      pk[1][p] = pkrtz_u(s1[2*p], s1[2*p+1]);
    }

    // ---- out^T += Vt . P^T
#pragma unroll
    for (int ks = 0; ks < 4; ++ks) {
      const int c = ks >> 1, base = (ks & 1) * 4;
      const u32 own0 = hi ? pk[c][base+2] : pk[c][base+0];
      const u32 own1 = hi ? pk[c][base+3] : pk[c][base+1];
      const u32 opp0 = hi ? pk[c][base+0] : pk[c][base+2];
      const u32 opp1 = hi ? pk[c][base+1] : pk[c][base+3];
      const u32 sh0 = (u32)__shfl_xor((int)opp0, 32);
      const u32 sh1 = (u32)__shfl_xor((int)opp1, 32);
      u32x4 bw;
      bw[0] = hi ? sh0 : own0;
      bw[1] = hi ? sh1 : own1;
      bw[2] = hi ? own0 : sh0;
      bw[3] = hi ? own1 : sh1;
      const f16x8 pb = __builtin_bit_cast(f16x8, bw);
      const int cs = ((ks * 2 + (hi ? 1 : 0)) ^ sw) * 8;
      const f16x8 va0 = *(const f16x8*)&vb[l31 * 64 + cs];
      const f16x8 va1 = *(const f16x8*)&vb[(32 + l31) * 64 + cs];
      acc0 = __builtin_amdgcn_mfma_f32_32x32x16_f16(va0, pb, acc0, 0, 0, 0);
      acc1 = __builtin_amdgcn_mfma_f32_32x32x16_f16(va1, pb, acc1, 0, 0, 0);
    }

    __syncthreads();
    cur ^= 1;
  }

  // ---- epilogue: out^T -> LDS transpose (72-pitch) -> coalesced store
  _Float16* tr = &smem[0][0][0] + wid * 2304;     // 32 rows x 72
  const float invl = 1.0f / l_run;
#pragma unroll
  for (int r = 0; r < 16; ++r) {
    const int d = (r & 3) + 8 * (r >> 2) + (hi ? 4 : 0);
    tr[l31 * 72 + d]      = (_Float16)(acc0[r] * invl);
    tr[l31 * 72 + 32 + d] = (_Float16)(acc1[r] * invl);
  }
  __syncthreads();
#pragma unroll
  for (int cc = 0; cc < 4; ++cc) {
    const int qq = cc * 8 + (lane >> 3), c8 = lane & 7;
    const f16x8 v = *(const f16x8*)&tr[qq * 72 + c8 * 8];
    *(f16x8*)&Om[(size_t)(q0w - wid * 32 + (wid ? 32 : 0) + qq) * DMODEL + h * HDIM + c8 * 8] = v;
  }
}

// ---------------------------------------------------------------- launch
extern "C" void kernel_launch(void* const* d_in, const int* in_sizes, int n_in,
                              void* d_out, int out_size, void* d_ws, size_t ws_size,
                              hipStream_t stream)
{
  const float* hs = (const float*)d_in[0];
  const float* ts = (const float*)d_in[1];
  const float* Wq = (const float*)d_in[2];
  const float* bq = (const float*)d_in[3];
  const float* Wk = (const float*)d_in[4];
  const float* bk = (const float*)d_in[5];
  const float* Wv = (const float*)d_in[6];
  const float* bv = (const float*)d_in[7];
  const float* Wo = (const float*)d_in[8];
  float* out = (float*)d_out;

  char* ws = (char*)d_ws;
  const size_t MB = 1024 * 1024;
  _Float16* hsb  = (_Float16*)(ws + 0 * MB);    // [S][D]   8MB
  _Float16* wqb  = (_Float16*)(ws + 8 * MB);    // [D][D]   2MB  (wq|wk|wv contiguous)
  _Float16* wkb  = (_Float16*)(ws + 10 * MB);
  _Float16* wvb  = (_Float16*)(ws + 12 * MB);
  _Float16* wob  = (_Float16*)(ws + 14 * MB);
  _Float16* Qb   = (_Float16*)(ws + 16 * MB);   // [S][D]   8MB
  _Float16* Kb   = (_Float16*)(ws + 24 * MB);   // [S][D]   8MB
  _Float16* Vtb  = (_Float16*)(ws + 32 * MB);   // [D][S]   8MB (transposed)
  _Float16* attb = (_Float16*)(ws + 40 * MB);   // [S][D]   8MB

  cast_f32_f16_k<<<dim3(4096), dim3(256), 0, stream>>>(hs, hsb, S_LEN * DMODEL);
  cast4_k<<<dim3(1024, 4), dim3(256), 0, stream>>>(Wq, Wk, Wv, Wo, wqb, wkb, wvb, wob);

  gemm_qkv<<<dim3(3072 / 128, S_LEN / 128), dim3(256), 0, stream>>>(
      hsb, wqb, bq, bk, bv, ts, Qb, Kb, Vtb);

  attn_fwd<<<dim3(1024), dim3(128), 0, stream>>>(Qb, Kb, Vtb, attb);

  gemm_o<<<dim3(DMODEL / 128, S_LEN / 128), dim3(256), 0, stream>>>(attb, wob, out);
}